// Round 2
// baseline (3980.468 us; speedup 1.0000x reference)
//
#include <hip/hip_runtime.h>

// DMPNN: N=50000 nodes, E=1.2M directed edges (pairs interleaved: rev(e)=e^1),
// DIM=64, STEPS=4. fp32 baseline.
//
// Inputs (d_in order):
// 0 node_feature [N,64] f32
// 1 edge_feature [E,64] f32
// 2 edge_src     [E]    i32
// 3 edge_dst     [E]    i32
// 4 rev_index    [E]    i32   (== e^1 by construction; exploited)
// 5 W_init  [128,64] f32
// 6 b_init  [64]     f32
// 7 W_steps [4,64,64] f32
// 8 b_steps [4,64]    f32
// 9 W_proj  [128,64] f32
// 10 b_proj [64]     f32
//
// Outputs: d_out = [ node_out (N*64) | h (E*64) ] f32.
// Workspace: agg (N*64 f32) | h0 (E*64 f32).

#define DIM 64

// ---- init: h0[e] = relu([nf[src[e]] || ef[e]] @ W_init + b); h = h0 ----
__global__ __launch_bounds__(256) void k_init(
    const float* __restrict__ nf, const float* __restrict__ ef,
    const int* __restrict__ src,
    const float* __restrict__ W, const float* __restrict__ b,
    float* __restrict__ h0, float* __restrict__ h, int E) {
  __shared__ float Ws[128 * 64];
  __shared__ float bs[64];
  __shared__ float ins[4][128];
  const int tid = threadIdx.x;
  const int wave = tid >> 6, lane = tid & 63;
  for (int i = tid; i < 128 * 64; i += 256) Ws[i] = W[i];
  if (tid < 64) bs[tid] = b[tid];
  __syncthreads();
  const int stride = gridDim.x * 4;
  for (int base = blockIdx.x * 4; base < E; base += stride) {
    const int e = base + wave;
    const bool valid = (e < E);
    if (valid) {
      const int s = src[e];
      ins[wave][lane]      = nf[(size_t)s * DIM + lane];
      ins[wave][64 + lane] = ef[(size_t)e * DIM + lane];
    }
    __syncthreads();
    if (valid) {
      float acc = bs[lane];
      #pragma unroll
      for (int k = 0; k < 128; ++k)
        acc = fmaf(ins[wave][k], Ws[k * 64 + lane], acc);
      acc = fmaxf(acc, 0.0f);
      h0[(size_t)e * DIM + lane] = acc;
      h [(size_t)e * DIM + lane] = acc;
    }
    __syncthreads();
  }
}

// ---- scatter: agg[dst[e]] += h[e] (agg pre-zeroed) ----
__global__ __launch_bounds__(256) void k_scatter(
    const float* __restrict__ h, const int* __restrict__ dst,
    float* __restrict__ agg, int E) {
  size_t i = (size_t)blockIdx.x * blockDim.x + threadIdx.x;
  const size_t total = (size_t)E * DIM;
  const size_t stride = (size_t)gridDim.x * blockDim.x;
  for (; i < total; i += stride) {
    const int e = (int)(i >> 6);
    atomicAdd(&agg[(size_t)dst[e] * DIM + (i & 63)], h[i]);
  }
}

// ---- step: per edge pair (2p, 2p+1): m = agg[src] - h[rev]; h = relu(h0 + m@W_t + b_t)
__global__ __launch_bounds__(256) void k_step(
    const float* __restrict__ agg, const int* __restrict__ src,
    const float* __restrict__ h0,
    const float* __restrict__ W, const float* __restrict__ b,
    float* __restrict__ h, int E) {
  __shared__ float Ws[64 * 64];
  __shared__ float bs[64];
  __shared__ float ins[4][2][64];
  const int tid = threadIdx.x;
  const int wave = tid >> 6, lane = tid & 63;
  for (int i = tid; i < 64 * 64; i += 256) Ws[i] = W[i];
  if (tid < 64) bs[tid] = b[tid];
  __syncthreads();
  const int P = E >> 1;  // pairs; rev(2p)=2p+1, rev(2p+1)=2p
  const int stride = gridDim.x * 4;
  for (int base = blockIdx.x * 4; base < P; base += stride) {
    const int p = base + wave;
    const bool valid = (p < P);
    float hv0 = 0.f, hv1 = 0.f;
    if (valid) {
      const size_t e0 = (size_t)2 * p;
      hv0 = h[e0 * DIM + lane];
      hv1 = h[(e0 + 1) * DIM + lane];
      const int s0 = src[e0], s1 = src[e0 + 1];
      ins[wave][0][lane] = agg[(size_t)s0 * DIM + lane] - hv1;  // m(e0)
      ins[wave][1][lane] = agg[(size_t)s1 * DIM + lane] - hv0;  // m(e1)
    }
    __syncthreads();
    if (valid) {
      float acc0 = bs[lane], acc1 = bs[lane];
      #pragma unroll
      for (int k = 0; k < 64; ++k) {
        const float w = Ws[k * 64 + lane];
        acc0 = fmaf(ins[wave][0][k], w, acc0);
        acc1 = fmaf(ins[wave][1][k], w, acc1);
      }
      const size_t e0 = (size_t)2 * p;
      const float h00 = h0[e0 * DIM + lane];
      const float h01 = h0[(e0 + 1) * DIM + lane];
      h[e0 * DIM + lane]       = fmaxf(h00 + acc0, 0.0f);
      h[(e0 + 1) * DIM + lane] = fmaxf(h01 + acc1, 0.0f);
    }
    __syncthreads();
  }
}

// ---- readout: node_out[n] = relu([nf[n] || agg[n]] @ W_proj + b_proj) ----
__global__ __launch_bounds__(256) void k_readout(
    const float* __restrict__ nf, const float* __restrict__ agg,
    const float* __restrict__ W, const float* __restrict__ b,
    float* __restrict__ out, int N) {
  __shared__ float Ws[128 * 64];
  __shared__ float bs[64];
  __shared__ float ins[4][128];
  const int tid = threadIdx.x;
  const int wave = tid >> 6, lane = tid & 63;
  for (int i = tid; i < 128 * 64; i += 256) Ws[i] = W[i];
  if (tid < 64) bs[tid] = b[tid];
  __syncthreads();
  const int stride = gridDim.x * 4;
  for (int base = blockIdx.x * 4; base < N; base += stride) {
    const int n = base + wave;
    const bool valid = (n < N);
    if (valid) {
      ins[wave][lane]      = nf[(size_t)n * DIM + lane];
      ins[wave][64 + lane] = agg[(size_t)n * DIM + lane];
    }
    __syncthreads();
    if (valid) {
      float acc = bs[lane];
      #pragma unroll
      for (int k = 0; k < 128; ++k)
        acc = fmaf(ins[wave][k], Ws[k * 64 + lane], acc);
      out[(size_t)n * DIM + lane] = fmaxf(acc, 0.0f);
    }
    __syncthreads();
  }
}

extern "C" void kernel_launch(void* const* d_in, const int* in_sizes, int n_in,
                              void* d_out, int out_size, void* d_ws, size_t ws_size,
                              hipStream_t stream) {
  const float* nf     = (const float*)d_in[0];
  const float* ef     = (const float*)d_in[1];
  const int*   src    = (const int*)d_in[2];
  const int*   dst    = (const int*)d_in[3];
  // d_in[4] rev_index unused: rev(e) = e^1 by construction
  const float* W_init = (const float*)d_in[5];
  const float* b_init = (const float*)d_in[6];
  const float* W_st   = (const float*)d_in[7];
  const float* b_st   = (const float*)d_in[8];
  const float* W_proj = (const float*)d_in[9];
  const float* b_proj = (const float*)d_in[10];

  const int N = in_sizes[0] / DIM;
  const int E = in_sizes[2];
  const int STEPS = in_sizes[7] / (DIM * DIM);

  float* node_out = (float*)d_out;
  float* h        = (float*)d_out + (size_t)N * DIM;  // h is an output slot
  float* agg      = (float*)d_ws;
  float* h0       = (float*)d_ws + (size_t)N * DIM;

  const int gInit = 1024, gStep = 2048, gScat = 4096, gRead = 1024;

  k_init<<<gInit, 256, 0, stream>>>(nf, ef, src, W_init, b_init, h0, h, E);
  for (int t = 0; t < STEPS; ++t) {
    hipMemsetAsync(agg, 0, (size_t)N * DIM * sizeof(float), stream);
    k_scatter<<<gScat, 256, 0, stream>>>(h, dst, agg, E);
    k_step<<<gStep, 256, 0, stream>>>(agg, src, h0,
                                      W_st + (size_t)t * DIM * DIM,
                                      b_st + (size_t)t * DIM, h, E);
  }
  hipMemsetAsync(agg, 0, (size_t)N * DIM * sizeof(float), stream);
  k_scatter<<<gScat, 256, 0, stream>>>(h, dst, agg, E);
  k_readout<<<gRead, 256, 0, stream>>>(nf, agg, W_proj, b_proj, node_out, N);
}